// Round 5
// baseline (173.136 us; speedup 1.0000x reference)
//
#include <hip/hip_runtime.h>
#include <hip/hip_bf16.h>
#include <math.h>

#define D_MODEL 1024
#define HD 128
#define SEQ 4096

typedef __bf16 bf16x8 __attribute__((ext_vector_type(8)));
typedef float f32x4 __attribute__((ext_vector_type(4)));
typedef unsigned int u32;
typedef u32 u32x4 __attribute__((ext_vector_type(4)));

__device__ __forceinline__ unsigned short f2bf(float f) {
    union { float f; u32 u; } c; c.f = f;
    u32 u = c.u;
    u = (u + 0x7fffu + ((u >> 16) & 1u)) >> 16;
    return (unsigned short)u;
}
__device__ __forceinline__ u32 pk2(float a, float b) {
    __hip_bfloat162 h = __float22bfloat162_rn(make_float2(a, b));
    union { __hip_bfloat162 h; u32 u; } c; c.h = h; return c.u;
}
// async global->LDS, 16B/lane; dest = wave-uniform base + lane*16
__device__ __forceinline__ void dma16(void* lds, const void* g) {
    __builtin_amdgcn_global_load_lds(
        (const __attribute__((address_space(1))) u32*)g,
        (__attribute__((address_space(3))) u32*)lds, 16, 0, 0);
}
// DMA completion is tracked only in the ISSUING wave's vmcnt (R7 race).
__device__ __forceinline__ void drain_dma()  { __builtin_amdgcn_s_waitcnt(0x0F70); } // vmcnt(0)

// ---------------------------------------------------------------------------
// LDS-transposed W -> Wt[n][k] bf16, n in [0,384). Q slice pre-scaled by
// 1/sqrt(128)*log2(e): scores exit QK^T MFMA in the log2 domain.
__global__ __launch_bounds__(256)
void wt_kernel(const float* __restrict__ Wq, const float* __restrict__ Wk,
               const float* __restrict__ Wv, unsigned short* __restrict__ Wt) {
    __shared__ float wsf[64][129];
    const int t = threadIdx.x;
    const int k0 = blockIdx.x * 64;
    const int mat = blockIdx.y;
    const float* W = (mat == 0) ? Wq : (mat == 1) ? Wk : Wv;
    const float sc = (mat == 0) ? (0.08838834764831845f * 1.4426950408889634f) : 1.0f;
    {
        const int r = t >> 2, c = (t & 3) * 32;
        const float* src = W + (size_t)(k0 + r) * HD + c;
        #pragma unroll
        for (int j = 0; j < 32; j += 4)
            *reinterpret_cast<f32x4*>(&wsf[r][c + j]) = *reinterpret_cast<const f32x4*>(src + j);
    }
    __syncthreads();
    const int n = t >> 1, ks = (t & 1) * 32;
    u32 ow[16];
    #pragma unroll
    for (int j = 0; j < 16; ++j)
        ow[j] = pk2(wsf[ks + 2 * j][n] * sc, wsf[ks + 2 * j + 1][n] * sc);
    unsigned short* dst = Wt + (size_t)(mat * HD + n) * D_MODEL + k0 + ks;
    #pragma unroll
    for (int j = 0; j < 4; ++j)
        *reinterpret_cast<u32x4*>(dst + j * 8) = (u32x4){ow[4*j], ow[4*j+1], ow[4*j+2], ow[4*j+3]};
}

// ---------------------------------------------------------------------------
// QKV projection v6 (R14): v1 geometry (3 blocks/CU -- best measured per-CU
// staging rate, 14.7 B/cy) + T4 counted-vmcnt raw barriers (v5's fix, which
// was only ever tested at the WORST-rate 1-block config). Rate model from
// R10-R13: proj time ~= staged bytes per CU / (8-15 B/cy) in every variant;
// m97 proves the same instruction sustains ~54 B/cy at 3 blocks x 4 waves --
// the untested cell is {3 blocks/CU, loads in flight across barriers}.
// Only change vs R0's harness-verified v1: drain_dma4+__syncthreads ->
// "s_waitcnt vmcnt(4) lgkmcnt(0)" + raw s_barrier (stage(it+1) stays in
// flight across the barrier; lgkmcnt(0) pre-barrier closes the ds_read-vs-
// DMA-overwrite window on buf (it+2)%3), plus setprio around the MFMA
// cluster. Math/addressing byte-identical to v1.
__global__ __launch_bounds__(256, 3)
void proj_kernel(const float* __restrict__ x, const unsigned short* __restrict__ Wt,
                 unsigned short* __restrict__ Qb, unsigned short* __restrict__ Kb,
                 unsigned short* __restrict__ Vt) {
    __shared__ __align__(1024) char ps[49152];   // x: 3 bufs @ [0,24K); Wt: 3 bufs @ [24K,48K)
    const int t = threadIdx.x;
    const int w = t >> 6, l = t & 63, li = l & 15, g2 = l >> 4;
    const int id = blockIdx.x;                 // 0..767
    const int grp = id / 24, win = id % 24;
    const int nbase = (win >> 3) * 128;        // slice 0:Q 1:K 2:V
    const int rowbase = (grp * 8 + (win & 7)) * 64;

    f32x4 acc[8];
    #pragma unroll
    for (int nt = 0; nt < 8; ++nt) acc[nt] = (f32x4){0.f, 0.f, 0.f, 0.f};

    const int lrow = l >> 3;                         // row within an 8-row issue
    const int xg = (l & 7) ^ (lrow & 6);             // x source granule
    const int wgr = (l & 7) ^ lrow;                  // Wt raw granule
    const int wrow_add = (wgr >> 2) << 6;            // +64 rows for upper k-half
    const int wkc = (wgr & 3) * 8;

    auto stage = [&](int k0, int buf) {
        #pragma unroll
        for (int j = 0; j < 2; ++j) {
            int r0 = w * 16 + 8 * j;
            dma16(ps + buf * 8192 + r0 * 128,
                  x + (size_t)(rowbase + r0 + lrow) * D_MODEL + k0 + xg * 4);
            dma16(ps + 24576 + buf * 8192 + r0 * 128,
                  Wt + (size_t)(nbase + r0 + lrow + wrow_add) * D_MODEL + k0 + wkc);
        }
    };

    stage(0, 0);
    stage(32, 1);
    for (int it = 0; it < 32; ++it) {
        const int buf = it % 3;
        // Counted wait: retire stage(it) (4 dma), keep stage(it+1) IN FLIGHT
        // across the raw barrier (no implicit vmcnt(0) drain).
        if (it < 31) asm volatile("s_waitcnt vmcnt(4) lgkmcnt(0)" ::: "memory");
        else         asm volatile("s_waitcnt vmcnt(0) lgkmcnt(0)" ::: "memory");
        __builtin_amdgcn_s_barrier();
        if (it + 2 < 32) stage((it + 2) * 32, (it + 2) % 3);
        const char* xb = ps + buf * 8192 + (w * 16 + li) * 128 + (((2 * g2) ^ (li & 6)) * 16);
        f32x4 x0 = *reinterpret_cast<const f32x4*>(xb);
        f32x4 x1 = *reinterpret_cast<const f32x4*>(xb + 16);
        union { u32 d[4]; bf16x8 v; } cva;
        cva.d[0] = pk2(x0[0], x0[1]); cva.d[1] = pk2(x0[2], x0[3]);
        cva.d[2] = pk2(x1[0], x1[1]); cva.d[3] = pk2(x1[2], x1[3]);
        bf16x8 af = cva.v;
        __builtin_amdgcn_s_setprio(1);
        #pragma unroll
        for (int nt = 0; nt < 8; ++nt) {
            bf16x8 bfr = *reinterpret_cast<const bf16x8*>(
                ps + 24576 + buf * 8192 + ((nt & 3) * 16 + li) * 128 +
                ((((nt >> 2) * 4 + g2) ^ (li & 7)) * 16));
            acc[nt] = __builtin_amdgcn_mfma_f32_16x16x32_bf16(af, bfr, acc[nt], 0, 0, 0);
        }
        __builtin_amdgcn_s_setprio(0);
    }

    if (nbase < 256) {
        unsigned short* P = nbase ? Kb : Qb;
        #pragma unroll
        for (int nt = 0; nt < 8; ++nt)
            #pragma unroll
            for (int r = 0; r < 4; ++r) {
                int grow = rowbase + w * 16 + g2 * 4 + r;
                P[(size_t)grow * HD + nt * 16 + li] = f2bf(acc[nt][r]);
            }
    } else {
        int grow0 = rowbase + w * 16 + g2 * 4;
        int b_ = grow0 >> 12, s_ = grow0 & 4095;
        #pragma unroll
        for (int nt = 0; nt < 8; ++nt) {
            ushort4 s4;
            s4.x = f2bf(acc[nt][0]); s4.y = f2bf(acc[nt][1]);
            s4.z = f2bf(acc[nt][2]); s4.w = f2bf(acc[nt][3]);
            *reinterpret_cast<ushort4*>(&Vt[((size_t)b_ * HD + nt * 16 + li) * SEQ + s_]) = s4;
        }
    }
}

// ---------------------------------------------------------------------------
// Flash causal attention, OPERAND-SWAPPED: scores computed as K.Q^T so the
// C-layout gives each lane 4 CONTIGUOUS keys for one query column. Softmax
// row-sum becomes a per-lane scalar; P^T packs to one b64 LDS write per frag;
// PV runs as A=V(d,k), B=P^T(k,q); O exits q=lane/d-contiguous -> f32x4 stores.
// Double-buffered K/V DMA staging (one barrier/iter), fixed-shift softmax.
// NOTE (R14 audit): attn's drain is structurally harmless -- its only
// in-flight stage must land before compute anyway (dist-1-optimal already).
// LDS 72 KB: K/V buf0 [0,32K), buf1 [32K,64K), P^T [64K,72K).
__global__ __launch_bounds__(256, 2)
void attn_kernel(const unsigned short* __restrict__ Qb, const unsigned short* __restrict__ Kb,
                 const unsigned short* __restrict__ Vt, float* __restrict__ outO,
                 unsigned short* __restrict__ Obf, float* __restrict__ Lbuf) {
    __shared__ __align__(1024) char smem[73728];
    const int t = threadIdx.x;
    const int w = t >> 6, l = t & 63, li = l & 15, g2 = l >> 4;
    const int qh = w >> 1, kh = w & 1;
    const int b = blockIdx.x & 3;
    const int u = blockIdx.x >> 2;
    const int g = 63 - (u >> 2);               // q-group, heavy first (LPT)
    const int c = u & 3;                       // key-range chunk
    const int R = g + 1;
    const int ts = (c * R) >> 2, te = ((c + 1) * R) >> 2;
    const int q0 = g * 64;
    const size_t rowb = (size_t)b * SEQ;
    const int koff = kh * 32;

    const unsigned short* KbB = Kb + rowb * HD;
    const unsigned short* VtB = Vt + (size_t)b * HD * SEQ;
    const int vgran = ((l & 7) ^ (l >> 3)) * 8;

    auto stage = [&](int it, char* base) {
        const int j0 = it * 64;
        #pragma unroll
        for (int j = 0; j < 4; ++j) {
            int rK = w * 16 + 4 * j + (l >> 4);
            dma16(base + (w * 16 + 4 * j) * 256,
                  KbB + (size_t)(j0 + rK) * 128 + (((l & 15) ^ (rK & 7)) * 8));
            int rV = w * 32 + 8 * j + (l >> 3);
            dma16(base + 16384 + (w * 32 + 8 * j) * 128,
                  VtB + (size_t)rV * SEQ + j0 + vgran);
        }
    };

    // Q as B-operand: B[k=d][n=q], lane n=li -> q, 8 contiguous d (= row-major load)
    bf16x8 qf[2][4];
    #pragma unroll
    for (int qt = 0; qt < 2; ++qt)
        #pragma unroll
        for (int ks = 0; ks < 4; ++ks)
            qf[qt][ks] = *reinterpret_cast<const bf16x8*>(
                Qb + (rowb + q0 + qh * 32 + qt * 16 + li) * HD + ks * 32 + g2 * 8);

    f32x4 acco[2][8];        // [qt][dt]: q=li, d=dt*16+g2*4+r
    #pragma unroll
    for (int qt = 0; qt < 2; ++qt)
        #pragma unroll
        for (int dt = 0; dt < 8; ++dt) acco[qt][dt] = (f32x4){0.f, 0.f, 0.f, 0.f};
    float ls[2] = {0.f, 0.f};   // per-lane: column q=li (per qt tile)

    const int gV = ((4 * kh + g2) ^ (li & 7)) * 16;   // V read granule offset

    if (ts < te) stage(ts, smem);
    for (int it = ts; it < te; ++it) {
        char* cbuf = smem + ((it - ts) & 1) * 32768;
        char* nbuf = smem + (((it - ts) & 1) ^ 1) * 32768;
        drain_dma();
        __syncthreads();
        if (it + 1 < te) stage(it + 1, nbuf);   // overlaps compute below

        // S^T = K.Q^T : rows=key (koff+kt*16+g2*4+r), cols=q (li)
        f32x4 accs[2][2];
        #pragma unroll
        for (int qt = 0; qt < 2; ++qt)
            #pragma unroll
            for (int kt = 0; kt < 2; ++kt) accs[qt][kt] = (f32x4){0.f, 0.f, 0.f, 0.f};
        #pragma unroll
        for (int kt = 0; kt < 2; ++kt) {
            const char* kb = cbuf + (koff + kt * 16 + li) * 256;
            #pragma unroll
            for (int ks = 0; ks < 4; ++ks) {
                bf16x8 kf = *reinterpret_cast<const bf16x8*>(kb + (((4 * ks + g2) ^ (li & 7)) * 16));
                accs[0][kt] = __builtin_amdgcn_mfma_f32_16x16x32_bf16(kf, qf[0][ks], accs[0][kt], 0, 0, 0);
                accs[1][kt] = __builtin_amdgcn_mfma_f32_16x16x32_bf16(kf, qf[1][ks], accs[1][kt], 0, 0, 0);
            }
        }

        const bool masked = (it == g);
        #pragma unroll
        for (int qt = 0; qt < 2; ++qt) {
            const int prow = qh * 32 + qt * 16 + li;       // block-local q
            #pragma unroll
            for (int kt = 0; kt < 2; ++kt) {
                float p[4];
                #pragma unroll
                for (int r = 0; r < 4; ++r) {
                    float s = accs[qt][kt][r];
                    if (masked && (koff + kt * 16 + g2 * 4 + r > prow)) s = -INFINITY;
                    p[r] = __builtin_amdgcn_exp2f(s - 16.0f);
                    ls[qt] += p[r];
                }
                // P^T[q][key] : lane writes 4 contiguous keys = one b64 store
                union { u32 d[2]; uint2 v; } pw;
                pw.d[0] = pk2(p[0], p[1]); pw.d[1] = pk2(p[2], p[3]);
                int gr = (kh * 4 + kt * 2 + (g2 >> 1)) ^ (prow & 7);
                *reinterpret_cast<uint2*>(
                    smem + 65536 + prow * 128 + gr * 16 + (g2 & 1) * 8) = pw.v;
            }
        }

        // In-wave P^T write->read only (same rows/granules); lgkmcnt orders.
        bf16x8 pb[2];
        #pragma unroll
        for (int qt = 0; qt < 2; ++qt) {
            const int prow = qh * 32 + qt * 16 + li;
            pb[qt] = *reinterpret_cast<const bf16x8*>(
                smem + 65536 + prow * 128 + (((kh * 4 + g2) ^ (prow & 7)) * 16));
        }
        #pragma unroll
        for (int dt = 0; dt < 8; ++dt) {
            bf16x8 va = *reinterpret_cast<const bf16x8*>(cbuf + 16384 + (dt * 16 + li) * 128 + gV);
            acco[0][dt] = __builtin_amdgcn_mfma_f32_16x16x32_bf16(va, pb[0], acco[0][dt], 0, 0, 0);
            acco[1][dt] = __builtin_amdgcn_mfma_f32_16x16x32_bf16(va, pb[1], acco[1][dt], 0, 0, 0);
        }
    }

    // per-lane l: combine the 4 key-quads (lanes 16 apart hold same q)
    #pragma unroll
    for (int qt = 0; qt < 2; ++qt) {
        ls[qt] += __shfl_xor(ls[qt], 16);
        ls[qt] += __shfl_xor(ls[qt], 32);
    }

    // combine kh halves via LDS overlay (stage buffers dead now)
    float (*Osum)[132] = (float(*)[132])smem;        // 64 x 128 (+4 pad) f32 = [0,33792)
    float* Lsh = (float*)(smem + 33792);             // [2][64]
    __syncthreads();
    if (l < 16) {
        Lsh[kh * 64 + qh * 32 + l]      = ls[0];
        Lsh[kh * 64 + qh * 32 + 16 + l] = ls[1];
    }
    if (kh == 0) {
        #pragma unroll
        for (int qt = 0; qt < 2; ++qt)
            #pragma unroll
            for (int dt = 0; dt < 8; ++dt)
                *reinterpret_cast<f32x4*>(
                    &Osum[qh * 32 + qt * 16 + li][dt * 16 + g2 * 4]) = acco[qt][dt];
    }
    __syncthreads();
    if (kh == 1) {
        #pragma unroll
        for (int qt = 0; qt < 2; ++qt)
            #pragma unroll
            for (int dt = 0; dt < 8; ++dt) {
                f32x4* p = reinterpret_cast<f32x4*>(
                    &Osum[qh * 32 + qt * 16 + li][dt * 16 + g2 * 4]);
                f32x4 v = *p;
                #pragma unroll
                for (int j = 0; j < 4; ++j) v[j] += acco[qt][dt][j];
                *p = v;
            }
    }
    __syncthreads();

    if (t < 64)
        Lbuf[(size_t)c * 16384 + rowb + q0 + t] = Lsh[t] + Lsh[64 + t];
    #pragma unroll
    for (int k = 0; k < 8; ++k) {
        int idx = t + k * 256;
        int row = idx >> 5, col = (idx & 31) * 4;
        f32x4 o = *reinterpret_cast<const f32x4*>(&Osum[row][col]);
        size_t grow = rowb + q0 + row;
        if (c == 3) {
            *reinterpret_cast<f32x4*>(&outO[grow * HD + col]) = o;
        } else {
            union { u32 d[2]; uint2 v; } pkd;
            pkd.d[0] = pk2(o[0], o[1]); pkd.d[1] = pk2(o[2], o[3]);
            *reinterpret_cast<uint2*>(&Obf[(size_t)c * 2097152 + grow * HD + col]) = pkd.v;
        }
    }
}

// ---------------------------------------------------------------------------
// Merge: out = (Obf[0]+Obf[1]+Obf[2]+out) / (l0+l1+l2+l3)
__global__ __launch_bounds__(256)
void merge_kernel(float* __restrict__ outO, const unsigned short* __restrict__ Obf,
                  const float* __restrict__ Lbuf) {
    int tid = blockIdx.x * 256 + threadIdx.x;
    #pragma unroll
    for (int k = 0; k < 4; ++k) {
        int idx = tid + k * 131072;
        int row = idx >> 5, col = (idx & 31) * 4;
        float lsum = Lbuf[row] + Lbuf[16384 + row] + Lbuf[32768 + row] + Lbuf[49152 + row];
        float inv = 1.f / lsum;
        f32x4 o = *reinterpret_cast<const f32x4*>(&outO[(size_t)row * HD + col]);
        #pragma unroll
        for (int cc = 0; cc < 3; ++cc) {
            ushort4 uu = *reinterpret_cast<const ushort4*>(
                &Obf[(size_t)cc * 2097152 + (size_t)row * HD + col]);
            union { u32 u; float f; } a, b2, c2, d2;
            a.u = (u32)uu.x << 16; b2.u = (u32)uu.y << 16;
            c2.u = (u32)uu.z << 16; d2.u = (u32)uu.w << 16;
            o[0] += a.f; o[1] += b2.f; o[2] += c2.f; o[3] += d2.f;
        }
        #pragma unroll
        for (int j = 0; j < 4; ++j) o[j] *= inv;
        *reinterpret_cast<f32x4*>(&outO[(size_t)row * HD + col]) = o;
    }
}

// ---------------------------------------------------------------------------
extern "C" void kernel_launch(void* const* d_in, const int* in_sizes, int n_in,
                              void* d_out, int out_size, void* d_ws, size_t ws_size,
                              hipStream_t stream) {
    const float* x  = (const float*)d_in[0];
    const float* Wq = (const float*)d_in[1];
    const float* Wk = (const float*)d_in[2];
    const float* Wv = (const float*)d_in[3];
    float* out = (float*)d_out;

    char* ws = (char*)d_ws;
    unsigned short* Qb  = (unsigned short*)(ws);                        // 4 MB
    unsigned short* Kb  = (unsigned short*)(ws + ((size_t)4  << 20));   // 4 MB
    unsigned short* Vt  = (unsigned short*)(ws + ((size_t)8  << 20));   // 4 MB
    unsigned short* Wt  = (unsigned short*)(ws + ((size_t)12 << 20));   // 768 KB
    unsigned short* Obf = (unsigned short*)(ws + ((size_t)13 << 20));   // 3 x 4 MB
    float*          Lb  = (float*)(ws + ((size_t)25 << 20));            // 4 x 64 KB

    wt_kernel   <<<dim3(16, 3), dim3(256), 0, stream>>>(Wq, Wk, Wv, Wt);
    proj_kernel <<<dim3(768),   dim3(256), 0, stream>>>(x, Wt, Qb, Kb, Vt);
    attn_kernel <<<dim3(1024),  dim3(256), 0, stream>>>(Qb, Kb, Vt, out, Obf, Lb);
    merge_kernel<<<dim3(512),   dim3(256), 0, stream>>>(out, Obf, Lb);
}

// Round 6
// 165.936 us; speedup vs baseline: 1.0434x; 1.0434x over previous
//
#include <hip/hip_runtime.h>
#include <hip/hip_bf16.h>
#include <math.h>

#define D_MODEL 1024
#define HD 128
#define SEQ 4096

typedef __bf16 bf16x8 __attribute__((ext_vector_type(8)));
typedef float f32x4 __attribute__((ext_vector_type(4)));
typedef unsigned int u32;
typedef u32 u32x4 __attribute__((ext_vector_type(4)));

__device__ __forceinline__ unsigned short f2bf(float f) {
    union { float f; u32 u; } c; c.f = f;
    u32 u = c.u;
    u = (u + 0x7fffu + ((u >> 16) & 1u)) >> 16;
    return (unsigned short)u;
}
__device__ __forceinline__ u32 pk2(float a, float b) {
    __hip_bfloat162 h = __float22bfloat162_rn(make_float2(a, b));
    union { __hip_bfloat162 h; u32 u; } c; c.h = h; return c.u;
}
// async global->LDS, 16B/lane; dest = wave-uniform base + lane*16
__device__ __forceinline__ void dma16(void* lds, const void* g) {
    __builtin_amdgcn_global_load_lds(
        (const __attribute__((address_space(1))) u32*)g,
        (__attribute__((address_space(3))) u32*)lds, 16, 0, 0);
}
// DMA completion is tracked only in the ISSUING wave's vmcnt (R7 race).
__device__ __forceinline__ void drain_dma()  { __builtin_amdgcn_s_waitcnt(0x0F70); } // vmcnt(0)

// ---------------------------------------------------------------------------
// LDS-transposed W -> Wt[n][k] bf16, n in [0,384). Q slice pre-scaled by
// 1/sqrt(128)*log2(e): scores exit QK^T MFMA in the log2 domain.
__global__ __launch_bounds__(256)
void wt_kernel(const float* __restrict__ Wq, const float* __restrict__ Wk,
               const float* __restrict__ Wv, unsigned short* __restrict__ Wt) {
    __shared__ float wsf[64][129];
    const int t = threadIdx.x;
    const int k0 = blockIdx.x * 64;
    const int mat = blockIdx.y;
    const float* W = (mat == 0) ? Wq : (mat == 1) ? Wk : Wv;
    const float sc = (mat == 0) ? (0.08838834764831845f * 1.4426950408889634f) : 1.0f;
    {
        const int r = t >> 2, c = (t & 3) * 32;
        const float* src = W + (size_t)(k0 + r) * HD + c;
        #pragma unroll
        for (int j = 0; j < 32; j += 4)
            *reinterpret_cast<f32x4*>(&wsf[r][c + j]) = *reinterpret_cast<const f32x4*>(src + j);
    }
    __syncthreads();
    const int n = t >> 1, ks = (t & 1) * 32;
    u32 ow[16];
    #pragma unroll
    for (int j = 0; j < 16; ++j)
        ow[j] = pk2(wsf[ks + 2 * j][n] * sc, wsf[ks + 2 * j + 1][n] * sc);
    unsigned short* dst = Wt + (size_t)(mat * HD + n) * D_MODEL + k0 + ks;
    #pragma unroll
    for (int j = 0; j < 4; ++j)
        *reinterpret_cast<u32x4*>(dst + j * 8) = (u32x4){ow[4*j], ow[4*j+1], ow[4*j+2], ow[4*j+3]};
}

// ---------------------------------------------------------------------------
// QKV projection v7 (R15): MINIMIZE GLOBAL REQUESTS PER WAVE.
// Unified model from R10-R14 (+m97): per-BLOCK-iter time is ~constant whether
// 1/2/3 blocks share a CU (no throughput contention) and scales with global
// requests per wave: wall ~= (reqs/wave) x ~800cy. v1/v3/v5 all staged
// 125-130 KB/wave -> ~102k cy = 44us, regardless of prefetch depth, barrier
// type, dma count, transport. Fix: 16-wave (1024-thr) blocks, tile 64 rows x
// 384 cols, grid 256 (1/CU, one generation): 1 MB staged / 16 waves =
// 64 KB/wave = 2 dma16/wave/iter (balanced: waves 0-7 = 1 x + 1 Wt, waves
// 8-15 = 2 Wt). Quad-buffer 128KB LDS, counted-vmcnt raw barriers (v5/v6
// proven discipline), NO setprio (m190: hurts lockstep GEMM). Addressing
// formulas verbatim from harness-verified v3; wave decomp now 4x4 (16-row
// m-tile x 96-col slice, 6 MFMA/iter/wave).
__global__ __launch_bounds__(1024, 1)
void proj_kernel(const float* __restrict__ x, const unsigned short* __restrict__ Wt,
                 unsigned short* __restrict__ Qb, unsigned short* __restrict__ Kb,
                 unsigned short* __restrict__ Vt) {
    __shared__ __align__(1024) char ps[131072];  // x: [0,32K) 4x8KB; Wt: [32K,128K) 4x24KB
    const int t = threadIdx.x;
    const int w = t >> 6, l = t & 63, li = l & 15, g2 = l >> 4;
    const int mh = w >> 2, nq = w & 3;           // wave: rows mh*16..+16, cols nq*96..+96
    const int rowbase = blockIdx.x * 64;

    const int lr = l >> 3, lg = l & 7;           // dma: row-within-8, phys granule
    const int cg = lg ^ lr;                      // content code (= phys ^ (row&7))
    const int wn_add = (cg >> 2) * 192;          // Wt n-half packed in bit2
    const int wkq = (cg & 3) * 8;                // Wt k-granule (8 bf16 = 16B)

    // Exactly 2 dma16 per wave per iter (uniform vmcnt across waves).
    auto stage = [&](int it) {
        const int k0 = it * 32;
        const int buf = it & 3;
        char* xb = ps + buf * 8192;
        char* wbuf = ps + 32768 + buf * 24576;
        if (w < 8) {
            dma16(xb + w * 1024,
                  x + (size_t)(rowbase + w * 8 + lr) * D_MODEL + k0 + cg * 4);
            dma16(wbuf + w * 1024,
                  Wt + (size_t)(w * 8 + lr + wn_add) * D_MODEL + k0 + wkq);
        } else {
            const int j0 = 8 + (w - 8) * 2;
            dma16(wbuf + j0 * 1024,
                  Wt + (size_t)(j0 * 8 + lr + wn_add) * D_MODEL + k0 + wkq);
            dma16(wbuf + (j0 + 1) * 1024,
                  Wt + (size_t)((j0 + 1) * 8 + lr + wn_add) * D_MODEL + k0 + wkq);
        }
    };

    f32x4 acc[6];
    #pragma unroll
    for (int nt = 0; nt < 6; ++nt) acc[nt] = (f32x4){0.f, 0.f, 0.f, 0.f};

    stage(0); stage(1); stage(2);
    for (int it = 0; it < 32; ++it) {
        // Counted wait: retire stage(it) (2 dma/wave), keep it+1/it+2 in
        // flight ACROSS the raw barrier. lgkmcnt(0) closes the ds_read-vs-
        // DMA-overwrite window on the buf recycled by stage(it+3).
        if (it < 30)       asm volatile("s_waitcnt vmcnt(4) lgkmcnt(0)" ::: "memory");
        else if (it == 30) asm volatile("s_waitcnt vmcnt(2) lgkmcnt(0)" ::: "memory");
        else               asm volatile("s_waitcnt vmcnt(0) lgkmcnt(0)" ::: "memory");
        __builtin_amdgcn_s_barrier();
        if (it + 3 < 32) stage(it + 3);

        const char* xb = ps + (it & 3) * 8192;
        const char* wb = ps + 32768 + (it & 3) * 24576;

        // B-frags: n = nq*96 + nt*16 + li, k = g2*8..+8 (v3 formulas)
        bf16x8 bf[6];
        #pragma unroll
        for (int nt = 0; nt < 6; ++nt) {
            int r = (nq & 1) * 96 + nt * 16 + li;
            bf[nt] = *reinterpret_cast<const bf16x8*>(
                wb + r * 128 + ((((nq >> 1) * 4 + g2) ^ (li & 7)) * 16));
        }
        // A-frag: row mh*16+li, k = g2*8..+8 (f32 staged, cvt in-reg)
        {
            int row = mh * 16 + li;
            int p0 = ((2 * g2) ^ (li & 7)) * 16;
            f32x4 x0 = *reinterpret_cast<const f32x4*>(xb + row * 128 + p0);
            f32x4 x1 = *reinterpret_cast<const f32x4*>(xb + row * 128 + (p0 ^ 16));
            union { u32 d[4]; bf16x8 v; } cva;
            cva.d[0] = pk2(x0[0], x0[1]); cva.d[1] = pk2(x0[2], x0[3]);
            cva.d[2] = pk2(x1[0], x1[1]); cva.d[3] = pk2(x1[2], x1[3]);
            bf16x8 af = cva.v;
            #pragma unroll
            for (int nt = 0; nt < 6; ++nt)
                acc[nt] = __builtin_amdgcn_mfma_f32_16x16x32_bf16(af, bf[nt], acc[nt], 0, 0, 0);
        }
    }

    // Epilogue: C row = rowbase + mh*16 + g2*4 + r, col = nq*96 + nt*16 + li
    #pragma unroll
    for (int nt = 0; nt < 6; ++nt) {
        const int c0 = nq * 96 + nt * 16;
        const int m0 = rowbase + mh * 16 + g2 * 4;
        if (c0 < 256) {
            unsigned short* P = (c0 < 128) ? Qb : Kb;
            const int col = (c0 < 128 ? c0 : c0 - 128) + li;
            #pragma unroll
            for (int r = 0; r < 4; ++r)
                P[(size_t)(m0 + r) * HD + col] = f2bf(acc[nt][r]);
        } else {
            const int d = c0 - 256 + li;
            const int b_ = m0 >> 12, s_ = m0 & 4095;
            ushort4 s4;
            s4.x = f2bf(acc[nt][0]); s4.y = f2bf(acc[nt][1]);
            s4.z = f2bf(acc[nt][2]); s4.w = f2bf(acc[nt][3]);
            *reinterpret_cast<ushort4*>(&Vt[((size_t)b_ * HD + d) * SEQ + s_]) = s4;
        }
    }
}

// ---------------------------------------------------------------------------
// Flash causal attention, OPERAND-SWAPPED: scores computed as K.Q^T so the
// C-layout gives each lane 4 CONTIGUOUS keys for one query column. Softmax
// row-sum becomes a per-lane scalar; P^T packs to one b64 LDS write per frag;
// PV runs as A=V(d,k), B=P^T(k,q); O exits q=lane/d-contiguous -> f32x4 stores.
// Double-buffered K/V DMA staging (one barrier/iter), fixed-shift softmax.
// LDS 72 KB: K/V buf0 [0,32K), buf1 [32K,64K), P^T [64K,72K).
__global__ __launch_bounds__(256, 2)
void attn_kernel(const unsigned short* __restrict__ Qb, const unsigned short* __restrict__ Kb,
                 const unsigned short* __restrict__ Vt, float* __restrict__ outO,
                 unsigned short* __restrict__ Obf, float* __restrict__ Lbuf) {
    __shared__ __align__(1024) char smem[73728];
    const int t = threadIdx.x;
    const int w = t >> 6, l = t & 63, li = l & 15, g2 = l >> 4;
    const int qh = w >> 1, kh = w & 1;
    const int b = blockIdx.x & 3;
    const int u = blockIdx.x >> 2;
    const int g = 63 - (u >> 2);               // q-group, heavy first (LPT)
    const int c = u & 3;                       // key-range chunk
    const int R = g + 1;
    const int ts = (c * R) >> 2, te = ((c + 1) * R) >> 2;
    const int q0 = g * 64;
    const size_t rowb = (size_t)b * SEQ;
    const int koff = kh * 32;

    const unsigned short* KbB = Kb + rowb * HD;
    const unsigned short* VtB = Vt + (size_t)b * HD * SEQ;
    const int vgran = ((l & 7) ^ (l >> 3)) * 8;

    auto stage = [&](int it, char* base) {
        const int j0 = it * 64;
        #pragma unroll
        for (int j = 0; j < 4; ++j) {
            int rK = w * 16 + 4 * j + (l >> 4);
            dma16(base + (w * 16 + 4 * j) * 256,
                  KbB + (size_t)(j0 + rK) * 128 + (((l & 15) ^ (rK & 7)) * 8));
            int rV = w * 32 + 8 * j + (l >> 3);
            dma16(base + 16384 + (w * 32 + 8 * j) * 128,
                  VtB + (size_t)rV * SEQ + j0 + vgran);
        }
    };

    // Q as B-operand: B[k=d][n=q], lane n=li -> q, 8 contiguous d (= row-major load)
    bf16x8 qf[2][4];
    #pragma unroll
    for (int qt = 0; qt < 2; ++qt)
        #pragma unroll
        for (int ks = 0; ks < 4; ++ks)
            qf[qt][ks] = *reinterpret_cast<const bf16x8*>(
                Qb + (rowb + q0 + qh * 32 + qt * 16 + li) * HD + ks * 32 + g2 * 8);

    f32x4 acco[2][8];        // [qt][dt]: q=li, d=dt*16+g2*4+r
    #pragma unroll
    for (int qt = 0; qt < 2; ++qt)
        #pragma unroll
        for (int dt = 0; dt < 8; ++dt) acco[qt][dt] = (f32x4){0.f, 0.f, 0.f, 0.f};
    float ls[2] = {0.f, 0.f};   // per-lane: column q=li (per qt tile)

    const int gV = ((4 * kh + g2) ^ (li & 7)) * 16;   // V read granule offset

    if (ts < te) stage(ts, smem);
    for (int it = ts; it < te; ++it) {
        char* cbuf = smem + ((it - ts) & 1) * 32768;
        char* nbuf = smem + (((it - ts) & 1) ^ 1) * 32768;
        drain_dma();
        __syncthreads();
        if (it + 1 < te) stage(it + 1, nbuf);   // overlaps compute below

        // S^T = K.Q^T : rows=key (koff+kt*16+g2*4+r), cols=q (li)
        f32x4 accs[2][2];
        #pragma unroll
        for (int qt = 0; qt < 2; ++qt)
            #pragma unroll
            for (int kt = 0; kt < 2; ++kt) accs[qt][kt] = (f32x4){0.f, 0.f, 0.f, 0.f};
        #pragma unroll
        for (int kt = 0; kt < 2; ++kt) {
            const char* kb = cbuf + (koff + kt * 16 + li) * 256;
            #pragma unroll
            for (int ks = 0; ks < 4; ++ks) {
                bf16x8 kf = *reinterpret_cast<const bf16x8*>(kb + (((4 * ks + g2) ^ (li & 7)) * 16));
                accs[0][kt] = __builtin_amdgcn_mfma_f32_16x16x32_bf16(kf, qf[0][ks], accs[0][kt], 0, 0, 0);
                accs[1][kt] = __builtin_amdgcn_mfma_f32_16x16x32_bf16(kf, qf[1][ks], accs[1][kt], 0, 0, 0);
            }
        }

        const bool masked = (it == g);
        #pragma unroll
        for (int qt = 0; qt < 2; ++qt) {
            const int prow = qh * 32 + qt * 16 + li;       // block-local q
            #pragma unroll
            for (int kt = 0; kt < 2; ++kt) {
                float p[4];
                #pragma unroll
                for (int r = 0; r < 4; ++r) {
                    float s = accs[qt][kt][r];
                    if (masked && (koff + kt * 16 + g2 * 4 + r > prow)) s = -INFINITY;
                    p[r] = __builtin_amdgcn_exp2f(s - 16.0f);
                    ls[qt] += p[r];
                }
                // P^T[q][key] : lane writes 4 contiguous keys = one b64 store
                union { u32 d[2]; uint2 v; } pw;
                pw.d[0] = pk2(p[0], p[1]); pw.d[1] = pk2(p[2], p[3]);
                int gr = (kh * 4 + kt * 2 + (g2 >> 1)) ^ (prow & 7);
                *reinterpret_cast<uint2*>(
                    smem + 65536 + prow * 128 + gr * 16 + (g2 & 1) * 8) = pw.v;
            }
        }

        // In-wave P^T write->read only (same rows/granules); lgkmcnt orders.
        bf16x8 pb[2];
        #pragma unroll
        for (int qt = 0; qt < 2; ++qt) {
            const int prow = qh * 32 + qt * 16 + li;
            pb[qt] = *reinterpret_cast<const bf16x8*>(
                smem + 65536 + prow * 128 + (((kh * 4 + g2) ^ (prow & 7)) * 16));
        }
        #pragma unroll
        for (int dt = 0; dt < 8; ++dt) {
            bf16x8 va = *reinterpret_cast<const bf16x8*>(cbuf + 16384 + (dt * 16 + li) * 128 + gV);
            acco[0][dt] = __builtin_amdgcn_mfma_f32_16x16x32_bf16(va, pb[0], acco[0][dt], 0, 0, 0);
            acco[1][dt] = __builtin_amdgcn_mfma_f32_16x16x32_bf16(va, pb[1], acco[1][dt], 0, 0, 0);
        }
    }

    // per-lane l: combine the 4 key-quads (lanes 16 apart hold same q)
    #pragma unroll
    for (int qt = 0; qt < 2; ++qt) {
        ls[qt] += __shfl_xor(ls[qt], 16);
        ls[qt] += __shfl_xor(ls[qt], 32);
    }

    // combine kh halves via LDS overlay (stage buffers dead now)
    float (*Osum)[132] = (float(*)[132])smem;        // 64 x 128 (+4 pad) f32 = [0,33792)
    float* Lsh = (float*)(smem + 33792);             // [2][64]
    __syncthreads();
    if (l < 16) {
        Lsh[kh * 64 + qh * 32 + l]      = ls[0];
        Lsh[kh * 64 + qh * 32 + 16 + l] = ls[1];
    }
    if (kh == 0) {
        #pragma unroll
        for (int qt = 0; qt < 2; ++qt)
            #pragma unroll
            for (int dt = 0; dt < 8; ++dt)
                *reinterpret_cast<f32x4*>(
                    &Osum[qh * 32 + qt * 16 + li][dt * 16 + g2 * 4]) = acco[qt][dt];
    }
    __syncthreads();
    if (kh == 1) {
        #pragma unroll
        for (int qt = 0; qt < 2; ++qt)
            #pragma unroll
            for (int dt = 0; dt < 8; ++dt) {
                f32x4* p = reinterpret_cast<f32x4*>(
                    &Osum[qh * 32 + qt * 16 + li][dt * 16 + g2 * 4]);
                f32x4 v = *p;
                #pragma unroll
                for (int j = 0; j < 4; ++j) v[j] += acco[qt][dt][j];
                *p = v;
            }
    }
    __syncthreads();

    if (t < 64)
        Lbuf[(size_t)c * 16384 + rowb + q0 + t] = Lsh[t] + Lsh[64 + t];
    #pragma unroll
    for (int k = 0; k < 8; ++k) {
        int idx = t + k * 256;
        int row = idx >> 5, col = (idx & 31) * 4;
        f32x4 o = *reinterpret_cast<const f32x4*>(&Osum[row][col]);
        size_t grow = rowb + q0 + row;
        if (c == 3) {
            *reinterpret_cast<f32x4*>(&outO[grow * HD + col]) = o;
        } else {
            union { u32 d[2]; uint2 v; } pkd;
            pkd.d[0] = pk2(o[0], o[1]); pkd.d[1] = pk2(o[2], o[3]);
            *reinterpret_cast<uint2*>(&Obf[(size_t)c * 2097152 + grow * HD + col]) = pkd.v;
        }
    }
}

// ---------------------------------------------------------------------------
// Merge: out = (Obf[0]+Obf[1]+Obf[2]+out) / (l0+l1+l2+l3)
__global__ __launch_bounds__(256)
void merge_kernel(float* __restrict__ outO, const unsigned short* __restrict__ Obf,
                  const float* __restrict__ Lbuf) {
    int tid = blockIdx.x * 256 + threadIdx.x;
    #pragma unroll
    for (int k = 0; k < 4; ++k) {
        int idx = tid + k * 131072;
        int row = idx >> 5, col = (idx & 31) * 4;
        float lsum = Lbuf[row] + Lbuf[16384 + row] + Lbuf[32768 + row] + Lbuf[49152 + row];
        float inv = 1.f / lsum;
        f32x4 o = *reinterpret_cast<const f32x4*>(&outO[(size_t)row * HD + col]);
        #pragma unroll
        for (int cc = 0; cc < 3; ++cc) {
            ushort4 uu = *reinterpret_cast<const ushort4*>(
                &Obf[(size_t)cc * 2097152 + (size_t)row * HD + col]);
            union { u32 u; float f; } a, b2, c2, d2;
            a.u = (u32)uu.x << 16; b2.u = (u32)uu.y << 16;
            c2.u = (u32)uu.z << 16; d2.u = (u32)uu.w << 16;
            o[0] += a.f; o[1] += b2.f; o[2] += c2.f; o[3] += d2.f;
        }
        #pragma unroll
        for (int j = 0; j < 4; ++j) o[j] *= inv;
        *reinterpret_cast<f32x4*>(&outO[(size_t)row * HD + col]) = o;
    }
}

// ---------------------------------------------------------------------------
extern "C" void kernel_launch(void* const* d_in, const int* in_sizes, int n_in,
                              void* d_out, int out_size, void* d_ws, size_t ws_size,
                              hipStream_t stream) {
    const float* x  = (const float*)d_in[0];
    const float* Wq = (const float*)d_in[1];
    const float* Wk = (const float*)d_in[2];
    const float* Wv = (const float*)d_in[3];
    float* out = (float*)d_out;

    char* ws = (char*)d_ws;
    unsigned short* Qb  = (unsigned short*)(ws);                        // 4 MB
    unsigned short* Kb  = (unsigned short*)(ws + ((size_t)4  << 20));   // 4 MB
    unsigned short* Vt  = (unsigned short*)(ws + ((size_t)8  << 20));   // 4 MB
    unsigned short* Wt  = (unsigned short*)(ws + ((size_t)12 << 20));   // 768 KB
    unsigned short* Obf = (unsigned short*)(ws + ((size_t)13 << 20));   // 3 x 4 MB
    float*          Lb  = (float*)(ws + ((size_t)25 << 20));            // 4 x 64 KB

    wt_kernel   <<<dim3(16, 3), dim3(256), 0, stream>>>(Wq, Wk, Wv, Wt);
    proj_kernel <<<dim3(256),   dim3(1024), 0, stream>>>(x, Wt, Qb, Kb, Vt);
    attn_kernel <<<dim3(1024),  dim3(256), 0, stream>>>(Qb, Kb, Vt, out, Obf, Lb);
    merge_kernel<<<dim3(512),   dim3(256), 0, stream>>>(out, Obf, Lb);
}

// Round 7
// 163.738 us; speedup vs baseline: 1.0574x; 1.0134x over previous
//
#include <hip/hip_runtime.h>
#include <hip/hip_bf16.h>
#include <math.h>

#define D_MODEL 1024
#define HD 128
#define SEQ 4096

typedef __bf16 bf16x8 __attribute__((ext_vector_type(8)));
typedef float f32x4 __attribute__((ext_vector_type(4)));
typedef unsigned int u32;
typedef u32 u32x4 __attribute__((ext_vector_type(4)));

__device__ __forceinline__ unsigned short f2bf(float f) {
    union { float f; u32 u; } c; c.f = f;
    u32 u = c.u;
    u = (u + 0x7fffu + ((u >> 16) & 1u)) >> 16;
    return (unsigned short)u;
}
__device__ __forceinline__ u32 pk2(float a, float b) {
    __hip_bfloat162 h = __float22bfloat162_rn(make_float2(a, b));
    union { __hip_bfloat162 h; u32 u; } c; c.h = h; return c.u;
}
// async global->LDS, 16B/lane; dest = wave-uniform base + lane*16
__device__ __forceinline__ void dma16(void* lds, const void* g) {
    __builtin_amdgcn_global_load_lds(
        (const __attribute__((address_space(1))) u32*)g,
        (__attribute__((address_space(3))) u32*)lds, 16, 0, 0);
}
// DMA completion is tracked only in the ISSUING wave's vmcnt (R7 race).
__device__ __forceinline__ void drain_dma()  { __builtin_amdgcn_s_waitcnt(0x0F70); } // vmcnt(0)

// ---------------------------------------------------------------------------
// LDS-transposed W -> Wt[n][k] bf16, n in [0,384). Q slice pre-scaled by
// 1/sqrt(128)*log2(e): scores exit QK^T MFMA in the log2 domain.
__global__ __launch_bounds__(256)
void wt_kernel(const float* __restrict__ Wq, const float* __restrict__ Wk,
               const float* __restrict__ Wv, unsigned short* __restrict__ Wt) {
    __shared__ float wsf[64][129];
    const int t = threadIdx.x;
    const int k0 = blockIdx.x * 64;
    const int mat = blockIdx.y;
    const float* W = (mat == 0) ? Wq : (mat == 1) ? Wk : Wv;
    const float sc = (mat == 0) ? (0.08838834764831845f * 1.4426950408889634f) : 1.0f;
    {
        const int r = t >> 2, c = (t & 3) * 32;
        const float* src = W + (size_t)(k0 + r) * HD + c;
        #pragma unroll
        for (int j = 0; j < 32; j += 4)
            *reinterpret_cast<f32x4*>(&wsf[r][c + j]) = *reinterpret_cast<const f32x4*>(src + j);
    }
    __syncthreads();
    const int n = t >> 1, ks = (t & 1) * 32;
    u32 ow[16];
    #pragma unroll
    for (int j = 0; j < 16; ++j)
        ow[j] = pk2(wsf[ks + 2 * j][n] * sc, wsf[ks + 2 * j + 1][n] * sc);
    unsigned short* dst = Wt + (size_t)(mat * HD + n) * D_MODEL + k0 + ks;
    #pragma unroll
    for (int j = 0; j < 4; ++j)
        *reinterpret_cast<u32x4*>(dst + j * 8) = (u32x4){ow[4*j], ow[4*j+1], ow[4*j+2], ow[4*j+3]};
}

// ---------------------------------------------------------------------------
// QKV projection v7 (R15, kept as best-known ~43us): 16-wave blocks, 2 dma16
// per wave per iter, quad-buffer 128KB LDS, counted-vmcnt raw barriers.
// R16 model: proj wall = chip inbound bytes (256 MB: x 64 + Wt 192 redundant)
// / ~6 TB/s L3 fabric rate -- invariant to request count/prefetch/barrier
// type across v1-v7. Left unchanged this round to isolate attn's delta.
__global__ __launch_bounds__(1024, 1)
void proj_kernel(const float* __restrict__ x, const unsigned short* __restrict__ Wt,
                 unsigned short* __restrict__ Qb, unsigned short* __restrict__ Kb,
                 unsigned short* __restrict__ Vt) {
    __shared__ __align__(1024) char ps[131072];  // x: [0,32K) 4x8KB; Wt: [32K,128K) 4x24KB
    const int t = threadIdx.x;
    const int w = t >> 6, l = t & 63, li = l & 15, g2 = l >> 4;
    const int mh = w >> 2, nq = w & 3;           // wave: rows mh*16..+16, cols nq*96..+96
    const int rowbase = blockIdx.x * 64;

    const int lr = l >> 3, lg = l & 7;           // dma: row-within-8, phys granule
    const int cg = lg ^ lr;                      // content code (= phys ^ (row&7))
    const int wn_add = (cg >> 2) * 192;          // Wt n-half packed in bit2
    const int wkq = (cg & 3) * 8;                // Wt k-granule (8 bf16 = 16B)

    // Exactly 2 dma16 per wave per iter (uniform vmcnt across waves).
    auto stage = [&](int it) {
        const int k0 = it * 32;
        const int buf = it & 3;
        char* xb = ps + buf * 8192;
        char* wbuf = ps + 32768 + buf * 24576;
        if (w < 8) {
            dma16(xb + w * 1024,
                  x + (size_t)(rowbase + w * 8 + lr) * D_MODEL + k0 + cg * 4);
            dma16(wbuf + w * 1024,
                  Wt + (size_t)(w * 8 + lr + wn_add) * D_MODEL + k0 + wkq);
        } else {
            const int j0 = 8 + (w - 8) * 2;
            dma16(wbuf + j0 * 1024,
                  Wt + (size_t)(j0 * 8 + lr + wn_add) * D_MODEL + k0 + wkq);
            dma16(wbuf + (j0 + 1) * 1024,
                  Wt + (size_t)((j0 + 1) * 8 + lr + wn_add) * D_MODEL + k0 + wkq);
        }
    };

    f32x4 acc[6];
    #pragma unroll
    for (int nt = 0; nt < 6; ++nt) acc[nt] = (f32x4){0.f, 0.f, 0.f, 0.f};

    stage(0); stage(1); stage(2);
    for (int it = 0; it < 32; ++it) {
        if (it < 30)       asm volatile("s_waitcnt vmcnt(4) lgkmcnt(0)" ::: "memory");
        else if (it == 30) asm volatile("s_waitcnt vmcnt(2) lgkmcnt(0)" ::: "memory");
        else               asm volatile("s_waitcnt vmcnt(0) lgkmcnt(0)" ::: "memory");
        __builtin_amdgcn_s_barrier();
        if (it + 3 < 32) stage(it + 3);

        const char* xb = ps + (it & 3) * 8192;
        const char* wb = ps + 32768 + (it & 3) * 24576;

        bf16x8 bf[6];
        #pragma unroll
        for (int nt = 0; nt < 6; ++nt) {
            int r = (nq & 1) * 96 + nt * 16 + li;
            bf[nt] = *reinterpret_cast<const bf16x8*>(
                wb + r * 128 + ((((nq >> 1) * 4 + g2) ^ (li & 7)) * 16));
        }
        {
            int row = mh * 16 + li;
            int p0 = ((2 * g2) ^ (li & 7)) * 16;
            f32x4 x0 = *reinterpret_cast<const f32x4*>(xb + row * 128 + p0);
            f32x4 x1 = *reinterpret_cast<const f32x4*>(xb + row * 128 + (p0 ^ 16));
            union { u32 d[4]; bf16x8 v; } cva;
            cva.d[0] = pk2(x0[0], x0[1]); cva.d[1] = pk2(x0[2], x0[3]);
            cva.d[2] = pk2(x1[0], x1[1]); cva.d[3] = pk2(x1[2], x1[3]);
            bf16x8 af = cva.v;
            #pragma unroll
            for (int nt = 0; nt < 6; ++nt)
                acc[nt] = __builtin_amdgcn_mfma_f32_16x16x32_bf16(af, bf[nt], acc[nt], 0, 0, 0);
        }
    }

    #pragma unroll
    for (int nt = 0; nt < 6; ++nt) {
        const int c0 = nq * 96 + nt * 16;
        const int m0 = rowbase + mh * 16 + g2 * 4;
        if (c0 < 256) {
            unsigned short* P = (c0 < 128) ? Qb : Kb;
            const int col = (c0 < 128 ? c0 : c0 - 128) + li;
            #pragma unroll
            for (int r = 0; r < 4; ++r)
                P[(size_t)(m0 + r) * HD + col] = f2bf(acc[nt][r]);
        } else {
            const int d = c0 - 256 + li;
            const int b_ = m0 >> 12, s_ = m0 & 4095;
            ushort4 s4;
            s4.x = f2bf(acc[nt][0]); s4.y = f2bf(acc[nt][1]);
            s4.z = f2bf(acc[nt][2]); s4.w = f2bf(acc[nt][3]);
            *reinterpret_cast<ushort4*>(&Vt[((size_t)b_ * HD + d) * SEQ + s_]) = s4;
        }
    }
}

// ---------------------------------------------------------------------------
// Flash causal attention v2 (R16): QBLK 128 (was 64) to HALVE K/V L3 traffic.
// Model: attn wall ~= staged K/V bytes / ~6 TB/s fabric rate; QBLK=64 staged
// 266 MB (24 MB of K/V re-read ~11x across q-blocks) ~= 44us. Doubling the
// q-rows amortized per K/V tile -> 133 MB. All inner formulas (operand-swap
// K.Q^T, XOR swizzles, P^T packing, fixed-shift softmax) unchanged; wave
// decomp now 8 waves = 4 q-quarters x 2 key-halves; staging split over 8
// waves (4 dma16/wave); diagonal mask spans 2 key-tiles (d = it - 2g).
// LDS 80 KB: K/V buf0 [0,32K), buf1 [32K,64K), P^T 128x128B [64K,80K);
// epilogue overlays Osum 128x132 f32 [0,67584) + Lsh [67584,68608).
// 2 blocks/CU = 160 KB exact fit.
__global__ __launch_bounds__(512, 2)
void attn_kernel(const unsigned short* __restrict__ Qb, const unsigned short* __restrict__ Kb,
                 const unsigned short* __restrict__ Vt, float* __restrict__ outO,
                 unsigned short* __restrict__ Obf, float* __restrict__ Lbuf) {
    __shared__ __align__(1024) char smem[81920];
    const int t = threadIdx.x;
    const int w = t >> 6, l = t & 63, li = l & 15, g2 = l >> 4;
    const int qh = w >> 1, kh = w & 1;         // q-quarter (0..3), key-half
    const int b = blockIdx.x & 3;
    const int u = blockIdx.x >> 2;             // 0..127
    const int g = 31 - (u >> 2);               // q-group of 128, heavy first (LPT)
    const int c = u & 3;                       // key-range chunk
    const int R = 2 * g + 2;                   // key tiles of 64 needed
    const int ts = (c * R) >> 2, te = ((c + 1) * R) >> 2;
    const int q0 = g * 128;
    const size_t rowb = (size_t)b * SEQ;
    const int koff = kh * 32;

    const unsigned short* KbB = Kb + rowb * HD;
    const unsigned short* VtB = Vt + (size_t)b * HD * SEQ;
    const int vgran = ((l & 7) ^ (l >> 3)) * 8;

    // 8 waves x 4 dma16: K 64 rows x 256B (2 dma = 8 rows), V 128 rows x 128B
    // (2 dma = 16 rows). Same per-row swizzle formulas as QBLK=64 version.
    auto stage = [&](int it, char* base) {
        const int j0 = it * 64;
        #pragma unroll
        for (int j = 0; j < 2; ++j) {
            int rK = w * 8 + 4 * j + (l >> 4);
            dma16(base + (w * 8 + 4 * j) * 256,
                  KbB + (size_t)(j0 + rK) * 128 + (((l & 15) ^ (rK & 7)) * 8));
            int rV = w * 16 + 8 * j + (l >> 3);
            dma16(base + 16384 + (w * 16 + 8 * j) * 128,
                  VtB + (size_t)rV * SEQ + j0 + vgran);
        }
    };

    // Q as B-operand: B[k=d][n=q], lane n=li -> q, 8 contiguous d
    bf16x8 qf[2][4];
    #pragma unroll
    for (int qt = 0; qt < 2; ++qt)
        #pragma unroll
        for (int ks = 0; ks < 4; ++ks)
            qf[qt][ks] = *reinterpret_cast<const bf16x8*>(
                Qb + (rowb + q0 + qh * 32 + qt * 16 + li) * HD + ks * 32 + g2 * 8);

    f32x4 acco[2][8];        // [qt][dt]: q=li, d=dt*16+g2*4+r
    #pragma unroll
    for (int qt = 0; qt < 2; ++qt)
        #pragma unroll
        for (int dt = 0; dt < 8; ++dt) acco[qt][dt] = (f32x4){0.f, 0.f, 0.f, 0.f};
    float ls[2] = {0.f, 0.f};

    const int gV = ((4 * kh + g2) ^ (li & 7)) * 16;   // V read granule offset

    if (ts < te) stage(ts, smem);
    for (int it = ts; it < te; ++it) {
        char* cbuf = smem + ((it - ts) & 1) * 32768;
        char* nbuf = smem + (((it - ts) & 1) ^ 1) * 32768;
        drain_dma();
        __syncthreads();
        if (it + 1 < te) stage(it + 1, nbuf);   // overlaps compute below

        // S^T = K.Q^T : rows=key (koff+kt*16+g2*4+r), cols=q (li)
        f32x4 accs[2][2];
        #pragma unroll
        for (int qt = 0; qt < 2; ++qt)
            #pragma unroll
            for (int kt = 0; kt < 2; ++kt) accs[qt][kt] = (f32x4){0.f, 0.f, 0.f, 0.f};
        #pragma unroll
        for (int kt = 0; kt < 2; ++kt) {
            const char* kb = cbuf + (koff + kt * 16 + li) * 256;
            #pragma unroll
            for (int ks = 0; ks < 4; ++ks) {
                bf16x8 kf = *reinterpret_cast<const bf16x8*>(kb + (((4 * ks + g2) ^ (li & 7)) * 16));
                accs[0][kt] = __builtin_amdgcn_mfma_f32_16x16x32_bf16(kf, qf[0][ks], accs[0][kt], 0, 0, 0);
                accs[1][kt] = __builtin_amdgcn_mfma_f32_16x16x32_bf16(kf, qf[1][ks], accs[1][kt], 0, 0, 0);
            }
        }

        // diagonal spans 2 key-tiles now: d = it-2g in {0,1} partially masked
        const int dmask = it - 2 * g;
        #pragma unroll
        for (int qt = 0; qt < 2; ++qt) {
            const int prow = qh * 32 + qt * 16 + li;       // block-local q (0..127)
            #pragma unroll
            for (int kt = 0; kt < 2; ++kt) {
                float p[4];
                #pragma unroll
                for (int r = 0; r < 4; ++r) {
                    float s = accs[qt][kt][r];
                    if (dmask >= 0 && (dmask * 64 + koff + kt * 16 + g2 * 4 + r > prow))
                        s = -INFINITY;
                    p[r] = __builtin_amdgcn_exp2f(s - 16.0f);
                    ls[qt] += p[r];
                }
                union { u32 d[2]; uint2 v; } pw;
                pw.d[0] = pk2(p[0], p[1]); pw.d[1] = pk2(p[2], p[3]);
                int gr = (kh * 4 + kt * 2 + (g2 >> 1)) ^ (prow & 7);
                *reinterpret_cast<uint2*>(
                    smem + 65536 + prow * 128 + gr * 16 + (g2 & 1) * 8) = pw.v;
            }
        }

        // In-wave P^T write->read only (same rows/granules); lgkmcnt orders.
        bf16x8 pb[2];
        #pragma unroll
        for (int qt = 0; qt < 2; ++qt) {
            const int prow = qh * 32 + qt * 16 + li;
            pb[qt] = *reinterpret_cast<const bf16x8*>(
                smem + 65536 + prow * 128 + (((kh * 4 + g2) ^ (prow & 7)) * 16));
        }
        #pragma unroll
        for (int dt = 0; dt < 8; ++dt) {
            bf16x8 va = *reinterpret_cast<const bf16x8*>(cbuf + 16384 + (dt * 16 + li) * 128 + gV);
            acco[0][dt] = __builtin_amdgcn_mfma_f32_16x16x32_bf16(va, pb[0], acco[0][dt], 0, 0, 0);
            acco[1][dt] = __builtin_amdgcn_mfma_f32_16x16x32_bf16(va, pb[1], acco[1][dt], 0, 0, 0);
        }
    }

    // per-lane: combine the 4 key-quads (lanes 16 apart hold same q)
    #pragma unroll
    for (int qt = 0; qt < 2; ++qt) {
        ls[qt] += __shfl_xor(ls[qt], 16);
        ls[qt] += __shfl_xor(ls[qt], 32);
    }

    // combine kh halves via LDS overlay (stage buffers dead now)
    float (*Osum)[132] = (float(*)[132])smem;        // 128 x 132 f32 = [0,67584)
    float* Lsh = (float*)(smem + 67584);             // [2][128]
    __syncthreads();
    if (l < 16) {
        Lsh[kh * 128 + qh * 32 + l]      = ls[0];
        Lsh[kh * 128 + qh * 32 + 16 + l] = ls[1];
    }
    if (kh == 0) {
        #pragma unroll
        for (int qt = 0; qt < 2; ++qt)
            #pragma unroll
            for (int dt = 0; dt < 8; ++dt)
                *reinterpret_cast<f32x4*>(
                    &Osum[qh * 32 + qt * 16 + li][dt * 16 + g2 * 4]) = acco[qt][dt];
    }
    __syncthreads();
    if (kh == 1) {
        #pragma unroll
        for (int qt = 0; qt < 2; ++qt)
            #pragma unroll
            for (int dt = 0; dt < 8; ++dt) {
                f32x4* p = reinterpret_cast<f32x4*>(
                    &Osum[qh * 32 + qt * 16 + li][dt * 16 + g2 * 4]);
                f32x4 v = *p;
                #pragma unroll
                for (int j = 0; j < 4; ++j) v[j] += acco[qt][dt][j];
                *p = v;
            }
    }
    __syncthreads();

    if (t < 128)
        Lbuf[(size_t)c * 16384 + rowb + q0 + t] = Lsh[t] + Lsh[128 + t];
    #pragma unroll
    for (int k = 0; k < 8; ++k) {
        int idx = t + k * 512;
        int row = idx >> 5, col = (idx & 31) * 4;
        f32x4 o = *reinterpret_cast<const f32x4*>(&Osum[row][col]);
        size_t grow = rowb + q0 + row;
        if (c == 3) {
            *reinterpret_cast<f32x4*>(&outO[grow * HD + col]) = o;
        } else {
            union { u32 d[2]; uint2 v; } pkd;
            pkd.d[0] = pk2(o[0], o[1]); pkd.d[1] = pk2(o[2], o[3]);
            *reinterpret_cast<uint2*>(&Obf[(size_t)c * 2097152 + grow * HD + col]) = pkd.v;
        }
    }
}

// ---------------------------------------------------------------------------
// Merge: out = (Obf[0]+Obf[1]+Obf[2]+out) / (l0+l1+l2+l3)
__global__ __launch_bounds__(256)
void merge_kernel(float* __restrict__ outO, const unsigned short* __restrict__ Obf,
                  const float* __restrict__ Lbuf) {
    int tid = blockIdx.x * 256 + threadIdx.x;
    #pragma unroll
    for (int k = 0; k < 4; ++k) {
        int idx = tid + k * 131072;
        int row = idx >> 5, col = (idx & 31) * 4;
        float lsum = Lbuf[row] + Lbuf[16384 + row] + Lbuf[32768 + row] + Lbuf[49152 + row];
        float inv = 1.f / lsum;
        f32x4 o = *reinterpret_cast<const f32x4*>(&outO[(size_t)row * HD + col]);
        #pragma unroll
        for (int cc = 0; cc < 3; ++cc) {
            ushort4 uu = *reinterpret_cast<const ushort4*>(
                &Obf[(size_t)cc * 2097152 + (size_t)row * HD + col]);
            union { u32 u; float f; } a, b2, c2, d2;
            a.u = (u32)uu.x << 16; b2.u = (u32)uu.y << 16;
            c2.u = (u32)uu.z << 16; d2.u = (u32)uu.w << 16;
            o[0] += a.f; o[1] += b2.f; o[2] += c2.f; o[3] += d2.f;
        }
        #pragma unroll
        for (int j = 0; j < 4; ++j) o[j] *= inv;
        *reinterpret_cast<f32x4*>(&outO[(size_t)row * HD + col]) = o;
    }
}

// ---------------------------------------------------------------------------
extern "C" void kernel_launch(void* const* d_in, const int* in_sizes, int n_in,
                              void* d_out, int out_size, void* d_ws, size_t ws_size,
                              hipStream_t stream) {
    const float* x  = (const float*)d_in[0];
    const float* Wq = (const float*)d_in[1];
    const float* Wk = (const float*)d_in[2];
    const float* Wv = (const float*)d_in[3];
    float* out = (float*)d_out;

    char* ws = (char*)d_ws;
    unsigned short* Qb  = (unsigned short*)(ws);                        // 4 MB
    unsigned short* Kb  = (unsigned short*)(ws + ((size_t)4  << 20));   // 4 MB
    unsigned short* Vt  = (unsigned short*)(ws + ((size_t)8  << 20));   // 4 MB
    unsigned short* Wt  = (unsigned short*)(ws + ((size_t)12 << 20));   // 768 KB
    unsigned short* Obf = (unsigned short*)(ws + ((size_t)13 << 20));   // 3 x 4 MB
    float*          Lb  = (float*)(ws + ((size_t)25 << 20));            // 4 x 64 KB

    wt_kernel   <<<dim3(16, 3), dim3(256), 0, stream>>>(Wq, Wk, Wv, Wt);
    proj_kernel <<<dim3(256),   dim3(1024), 0, stream>>>(x, Wt, Qb, Kb, Vt);
    attn_kernel <<<dim3(512),   dim3(512), 0, stream>>>(Qb, Kb, Vt, out, Obf, Lb);
    merge_kernel<<<dim3(512),   dim3(256), 0, stream>>>(out, Obf, Lb);
}